// Round 9
// baseline (278.226 us; speedup 1.0000x reference)
//
#include <hip/hip_runtime.h>

typedef unsigned short u16;
typedef __attribute__((ext_vector_type(8))) short bf16x8;
typedef __attribute__((ext_vector_type(4))) float f32x4;

__device__ __forceinline__ u16 f2bu(float f) {
  union { float f; unsigned u; } v; v.f = f;
  unsigned r = v.u + 0x7fffu + ((v.u >> 16) & 1u);
  return (u16)(r >> 16);
}
__device__ __forceinline__ u16 f2bu_fast(float f) {   // round-half-up, 2 ops
  union { float f; unsigned u; } v; v.f = f;
  return (u16)((v.u + 0x8000u) >> 16);
}
__device__ __forceinline__ float b2f(u16 s) {
  union { unsigned u; float f; } v; v.u = ((unsigned)s) << 16;
  return v.f;
}
__device__ __forceinline__ bf16x8 cvt8(float4 a, float4 b) {
  bf16x8 r;
  r[0] = (short)f2bu(a.x); r[1] = (short)f2bu(a.y);
  r[2] = (short)f2bu(a.z); r[3] = (short)f2bu(a.w);
  r[4] = (short)f2bu(b.x); r[5] = (short)f2bu(b.y);
  r[6] = (short)f2bu(b.z); r[7] = (short)f2bu(b.w);
  return r;
}
__device__ __forceinline__ f32x4 mfma16(bf16x8 a, bf16x8 b, f32x4 c) {
  return __builtin_amdgcn_mfma_f32_16x16x32_bf16(a, b, c, 0, 0, 0);
}

// ---------------- fp32 -> bf16 bulk convert (8 elem/thread)
__global__ __launch_bounds__(256) void prep_bf16_k(const float* __restrict__ src,
                                                   u16* __restrict__ dst, int n) {
  int idx = (blockIdx.x * 256 + threadIdx.x) * 8;
  if (idx < n) {
    float4 a = *(const float4*)(src + idx);
    float4 b = *(const float4*)(src + idx + 4);
    *(bf16x8*)(dst + idx) = cvt8(a, b);
  }
}

// ---------------- table prep: bf16 table [160][64] (pad rows zero) + transpose [64][160]
__global__ void prep_table_k(const float* __restrict__ tbl,
                             u16* __restrict__ tb, u16* __restrict__ tbT) {
  int t = threadIdx.x;
  for (int idx = t; idx < 160 * 64; idx += 256) {
    int r = idx >> 6, d = idx & 63;
    float v = (r < 129) ? tbl[r * 64 + d] : 0.f;
    u16 bv = f2bu(v);
    tb[r * 64 + d] = bv;
    tbT[d * 160 + r] = bv;
  }
}

// ---------------- mask prep: int32 [4][1024][1024] -> transposed 16-bit words
// bmq[b][q][wv][fr] bit nt = mask[b][q][wv*256 + nt*16 + fr]
__global__ __launch_bounds__(256) void prep_maskq_k(const int* __restrict__ mask,
                                                    u16* __restrict__ bmq) {
  int t = blockIdx.x * 256 + threadIdx.x;     // 262144 total
  int fr = t & 15, wv = (t >> 4) & 3;
  int q = (t >> 6) & 1023, b = t >> 16;
  const int* mrow = mask + ((size_t)b * 1024 + q) * 1024 + wv * 256 + fr;
  unsigned bits = 0;
#pragma unroll
  for (int nt = 0; nt < 16; ++nt) bits |= (mrow[nt * 16] != 0 ? 1u : 0u) << nt;
  bmq[t] = (u16)bits;
}

// ---------------- QKV GEMM (bf16 in): C[4096][3072] = xb @ wb^T + b, scatter q/k/v
__global__ __launch_bounds__(256) void gemm_qkv_k(
    const u16* __restrict__ A, const u16* __restrict__ Bw,
    const float* __restrict__ bias,
    u16* __restrict__ qb, u16* __restrict__ kb, u16* __restrict__ vt) {
  __shared__ u16 As[128][40];
  __shared__ u16 Bs[128][40];
  const int tid = threadIdx.x;
  const int l = tid & 63, w = tid >> 6;
  const int wr = w >> 1, wc = w & 1;
  const int fr = l & 15, kq = (l >> 4) * 8;
  const int bid = blockIdx.x;
  const int tn = (bid % 24) * 128, tm = (bid / 24) * 128;
  const int sr = tid >> 1, sc = (tid & 1) * 16;
  const u16* Ag = A + (size_t)(tm + sr) * 1024 + sc;
  const u16* Bg = Bw + (size_t)(tn + sr) * 1024 + sc;
  f32x4 acc[4][4] = {};
  auto compute = [&]() {
    bf16x8 af[4], bfv[4];
#pragma unroll
    for (int mi = 0; mi < 4; ++mi) af[mi] = *(const bf16x8*)&As[wr * 64 + mi * 16 + fr][kq];
#pragma unroll
    for (int ni = 0; ni < 4; ++ni) bfv[ni] = *(const bf16x8*)&Bs[wc * 64 + ni * 16 + fr][kq];
#pragma unroll
    for (int mi = 0; mi < 4; ++mi)
#pragma unroll
      for (int ni = 0; ni < 4; ++ni)
        acc[mi][ni] = mfma16(af[mi], bfv[ni], acc[mi][ni]);
  };
  bf16x8 aX0, aX1, bX0, bX1, aY0, aY1, bY0, bY1;
  aX0 = *(const bf16x8*)(Ag);     aX1 = *(const bf16x8*)(Ag + 8);
  bX0 = *(const bf16x8*)(Bg);     bX1 = *(const bf16x8*)(Bg + 8);
#pragma unroll 1
  for (int kt = 0; kt < 32; kt += 2) {
    __syncthreads();
    *(bf16x8*)&As[sr][sc] = aX0; *(bf16x8*)&As[sr][sc + 8] = aX1;
    *(bf16x8*)&Bs[sr][sc] = bX0; *(bf16x8*)&Bs[sr][sc + 8] = bX1;
    __syncthreads();
    aY0 = *(const bf16x8*)(Ag + (kt + 1) * 32);
    aY1 = *(const bf16x8*)(Ag + (kt + 1) * 32 + 8);
    bY0 = *(const bf16x8*)(Bg + (kt + 1) * 32);
    bY1 = *(const bf16x8*)(Bg + (kt + 1) * 32 + 8);
    compute();
    __syncthreads();
    *(bf16x8*)&As[sr][sc] = aY0; *(bf16x8*)&As[sr][sc + 8] = aY1;
    *(bf16x8*)&Bs[sr][sc] = bY0; *(bf16x8*)&Bs[sr][sc + 8] = bY1;
    __syncthreads();
    if (kt + 2 < 32) {
      aX0 = *(const bf16x8*)(Ag + (kt + 2) * 32);
      aX1 = *(const bf16x8*)(Ag + (kt + 2) * 32 + 8);
      bX0 = *(const bf16x8*)(Bg + (kt + 2) * 32);
      bX1 = *(const bf16x8*)(Bg + (kt + 2) * 32 + 8);
    }
    compute();
  }
#pragma unroll
  for (int mi = 0; mi < 4; ++mi)
#pragma unroll
    for (int ni = 0; ni < 4; ++ni)
#pragma unroll
      for (int j = 0; j < 4; ++j) {
        int gm = tm + wr * 64 + mi * 16 + (l >> 4) * 4 + j;
        int gn = tn + wc * 64 + ni * 16 + fr;
        float v = acc[mi][ni][j] + bias[gn];
        int b = gm >> 10, s = gm & 1023;
        unsigned gnu = (unsigned)gn;
        unsigned h = gnu / 192u;
        unsigned rem = gnu - h * 192u;
        unsigned which = rem >> 6, d = rem & 63u;
        int bh = b * 16 + (int)h;
        u16 bv = f2bu(v);
        if (which == 0u)      qb[((size_t)bh * 1024 + s) * 64 + d] = bv;
        else if (which == 1u) kb[((size_t)bh * 1024 + s) * 64 + d] = bv;
        else                  vt[((size_t)bh * 64 + d) * 1024 + s] = bv;
      }
}

// ---------------- attention: flash-chunked; 1 block = (b,h,16 q-rows); 4 waves
#define PCSTR 264   // p-chunk row stride u16: 528B = 33 16B slots (odd -> 2-way max)
#define SSTR 136    // band/qrel row stride u16: 272B = 17 slots (odd)
__global__ __launch_bounds__(256) void attn_k(
    const u16* __restrict__ qb, const u16* __restrict__ kb,
    const u16* __restrict__ vt, const u16* __restrict__ tb,
    const u16* __restrict__ tbT, const u16* __restrict__ bmq,
    u16* __restrict__ vals) {
  __shared__ u16 pc[16 * PCSTR];       // p~ chunk (256 cols, bf16)
  __shared__ u16 qr[16 * SSTR];        // qrel bf16 (persistent)
  __shared__ u16 qs[16 * SSTR];        // band region (persistent, pre-zeroed)
  __shared__ float wsum[4][16], wsumA[4][16], wsumB[4][16];
  const int tid = threadIdx.x;
  const int l = tid & 63, w = tid >> 6;
  const int fr = l & 15, g = l >> 4, kq = g * 8;
  const int blk = ((int)blockIdx.x & 7) * 512 + ((int)blockIdx.x >> 3);  // XCD swizzle
  const int qt = blk & 63, bh = blk >> 6;
  const int b = bh >> 4, h = bh & 15;
  const int qbase = qt * 16;
  const int dcol = w * 16 + fr;
  const u16* qrow = qb + ((size_t)bh * 1024 + qbase) * 64;
  bf16x8 qa0 = *(const bf16x8*)(qrow + fr * 64 + kq);
  bf16x8 qa1 = *(const bf16x8*)(qrow + fr * 64 + 32 + kq);
  const float t0v = b2f(tb[dcol]);
  const float t128v = b2f(tb[128 * 64 + dcol]);
  const u16* kbase = kb + (size_t)bh * 65536;
  const u16* vbase = vt + (size_t)bh * 65536;
  // zero band buffer (16 rows x 17 slots of 8)
  for (int i = tid; i < 272; i += 256) {
    bf16x8 z = {};
    *(bf16x8*)&qs[(i / 17) * SSTR + (i % 17) * 8] = z;
  }
  // K tile loader: flat tile index tt in 0..15; col = chunk*256 + w*64 + (tt&3)*16
  auto ldK = [&](int tt, bf16x8& lo, bf16x8& hi) {
    int col = ((tt >> 2) << 8) + (w << 6) + ((tt & 3) << 4);
    const u16* kp = kbase + (size_t)(col + fr) * 64 + kq;
    lo = *(const bf16x8*)(kp);
    hi = *(const bf16x8*)(kp + 32);
  };
  bf16x8 kf[2][2];
  ldK(0, kf[0][0], kf[0][1]);
  // pass 0: qrel[row][r] = q . table[r]  (bf16 into qr)
  for (int t = w; t < 9; t += 4) {
    int r0 = t * 16;
    const u16* tp = tb + (r0 + fr) * 64 + kq;
    bf16x8 tb0 = *(const bf16x8*)(tp);
    bf16x8 tb1 = *(const bf16x8*)(tp + 32);
    f32x4 a = {0.f, 0.f, 0.f, 0.f};
    a = mfma16(qa0, tb0, a);
    a = mfma16(qa1, tb1, a);
    int rg = r0 + fr;
    if (rg < 129) {
#pragma unroll
      for (int j = 0; j < 4; ++j) qr[(g * 4 + j) * SSTR + rg] = f2bu(a[j]);
    }
  }
  __syncthreads();
  float q0r[4], q128r[4];
#pragma unroll
  for (int j = 0; j < 4; ++j) {
    int row = g * 4 + j;
    q0r[j] = b2f(qr[row * SSTR]);
    q128r[j] = b2f(qr[row * SSTR + 128]);
  }
  // mask word loader (chunk-indexed)
  auto ldM = [&](int c, unsigned* dst) {
#pragma unroll
    for (int j = 0; j < 4; ++j)
      dst[j] = bmq[(((size_t)b * 1024 + qbase + g * 4 + j) * 4 + c) * 16 + fr];
  };
  unsigned bmX[4], bmY[4];
  ldM(0, bmX);
  const float C1 = 0.18033688011112042f;   // 0.125*log2(e)
  const float C2 = 17.31234049066756f;     // 12*log2(e)
  float ps[4] = {0.f, 0.f, 0.f, 0.f};
  float psA[4] = {0.f, 0.f, 0.f, 0.f};
  float psB[4] = {0.f, 0.f, 0.f, 0.f};
  f32x4 acc = {0.f, 0.f, 0.f, 0.f};        // PV accumulator (this wave's 16 d-cols)
  auto tileC = [&](int ncol, int bsh, const unsigned* bm, bf16x8 k0, bf16x8 k1) {
    int kgl = ncol + fr;
    int lcol = (ncol & 255) + fr;          // col within chunk
    f32x4 a = {0.f, 0.f, 0.f, 0.f};
    a = mfma16(qa0, k0, a);
    a = mfma16(qa1, k1, a);
    if (ncol + 79 <= qbase) {              // whole tile: rdx = 0
#pragma unroll
      for (int j = 0; j < 4; ++j) {
        float s = a[j] + q0r[j];
        float arg = ((bm[j] >> bsh) & 1u) ? __builtin_fmaf(s, C1, -C2) : -1e30f;
        float e = __builtin_amdgcn_exp2f(arg);
        ps[j] += e; psA[j] += e;
        pc[(g * 4 + j) * PCSTR + lcol] = f2bu_fast(e);
      }
    } else if (ncol >= qbase + 79) {       // whole tile: rdx = 128
#pragma unroll
      for (int j = 0; j < 4; ++j) {
        float s = a[j] + q128r[j];
        float arg = ((bm[j] >> bsh) & 1u) ? __builtin_fmaf(s, C1, -C2) : -1e30f;
        float e = __builtin_amdgcn_exp2f(arg);
        ps[j] += e; psB[j] += e;
        pc[(g * 4 + j) * PCSTR + lcol] = f2bu_fast(e);
      }
    } else {                                // mixed tile
#pragma unroll
      for (int j = 0; j < 4; ++j) {
        int row = g * 4 + j;
        int q = qbase + row;
        int dd = kgl - q;
        int rdx = dd < -64 ? 0 : (dd > 64 ? 128 : dd + 64);
        bool ov = (q >= 1 && q <= 1022);
        if (ov && kgl == 0) rdx = 0;
        if (ov && kgl == 1023) rdx = 128;
        float s = a[j] + b2f(qr[row * SSTR + rdx]);
        float arg = ((bm[j] >> bsh) & 1u) ? __builtin_fmaf(s, C1, -C2) : -1e30f;
        float e = __builtin_amdgcn_exp2f(arg);
        ps[j] += e;
        psA[j] += (rdx == 0) ? e : 0.f;
        psB[j] += (rdx == 128) ? e : 0.f;
        pc[row * PCSTR + lcol] = f2bu_fast(e);
      }
    }
  };
#pragma unroll 1
  for (int c = 0; c < 4; ++c) {
    // issue V loads for this chunk (held through pass 1, consumed in PV)
    const u16* vch = vbase + (size_t)dcol * 1024 + c * 256 + kq;
    bf16x8 vv0 = *(const bf16x8*)(vch);
    bf16x8 vv1 = *(const bf16x8*)(vch + 32);
    bf16x8 vv2 = *(const bf16x8*)(vch + 64);
    bf16x8 vv3 = *(const bf16x8*)(vch + 96);
    bf16x8 vv4 = *(const bf16x8*)(vch + 128);
    bf16x8 vv5 = *(const bf16x8*)(vch + 160);
    bf16x8 vv6 = *(const bf16x8*)(vch + 192);
    bf16x8 vv7 = *(const bf16x8*)(vch + 224);
    if (c < 3) ldM(c + 1, bmY);
    // pass 1: 4 tiles, depth-1 K prefetch (rotation period 2 aligns with 4 tiles)
#pragma unroll
    for (int t = 0; t < 4; ++t) {
      int tt = c * 4 + t;
      if (tt < 15) ldK(tt + 1, kf[(t + 1) & 1][0], kf[(t + 1) & 1][1]);
      tileC(c * 256 + w * 64 + t * 16, w * 4 + t, bmX, kf[t & 1][0], kf[t & 1][1]);
    }
    __syncthreads();   // pc ready
    // PV partial: 8 MFMA over this chunk
    {
      const u16* ar = pc + fr * PCSTR + kq;
      acc = mfma16(*(const bf16x8*)(ar), vv0, acc);
      acc = mfma16(*(const bf16x8*)(ar + 32), vv1, acc);
      acc = mfma16(*(const bf16x8*)(ar + 64), vv2, acc);
      acc = mfma16(*(const bf16x8*)(ar + 96), vv3, acc);
      acc = mfma16(*(const bf16x8*)(ar + 128), vv4, acc);
      acc = mfma16(*(const bf16x8*)(ar + 160), vv5, acc);
      acc = mfma16(*(const bf16x8*)(ar + 192), vv6, acc);
      acc = mfma16(*(const bf16x8*)(ar + 224), vv7, acc);
    }
    // incremental band gather (k within this chunk)
    {
      int row2 = tid >> 4;
      int rb = (tid & 15) * 8;
      int q2 = qbase + row2;
      bool ov2 = (q2 >= 1 && q2 <= 1022);
#pragma unroll
      for (int i = 0; i < 8; ++i) {
        int r = rb + i;
        int k = q2 - 64 + r;
        if (r >= 1 && k >= (c << 8) && k < ((c + 1) << 8)) {
          u16 val = pc[row2 * PCSTR + (k - (c << 8))];
          if (!(ov2 && (k == 0 || k == 1023))) qs[row2 * SSTR + r] = val;
        }
      }
    }
    __syncthreads();   // pc free for next chunk
#pragma unroll
    for (int j = 0; j < 4; ++j) bmX[j] = bmY[j];
  }
  // reduce row sums across the 16-lane groups, deposit per wave
#pragma unroll
  for (int j = 0; j < 4; ++j) {
#pragma unroll
    for (int off = 1; off <= 8; off <<= 1) {
      ps[j] += __shfl_xor(ps[j], off);
      psA[j] += __shfl_xor(psA[j], off);
      psB[j] += __shfl_xor(psB[j], off);
    }
  }
  if (fr == 0) {
#pragma unroll
    for (int j = 0; j < 4; ++j) {
      wsum[w][g * 4 + j] = ps[j];
      wsumA[w][g * 4 + j] = psA[j];
      wsumB[w][g * 4 + j] = psB[j];
    }
  }
  __syncthreads();
  // band MFMAs (r=1..127) + rank-1 r=0/128 + normalize + store
  {
    const u16* tq = tbT + dcol * 160 + kq;
    bf16x8 tf0 = *(const bf16x8*)(tq);
    bf16x8 tf1 = *(const bf16x8*)(tq + 32);
    bf16x8 tf2 = *(const bf16x8*)(tq + 64);
    bf16x8 tf3 = *(const bf16x8*)(tq + 96);
    const u16* srow = qs + fr * SSTR + kq;
    acc = mfma16(*(const bf16x8*)(srow), tf0, acc);
    acc = mfma16(*(const bf16x8*)(srow + 32), tf1, acc);
    acc = mfma16(*(const bf16x8*)(srow + 64), tf2, acc);
    acc = mfma16(*(const bf16x8*)(srow + 96), tf3, acc);
  }
#pragma unroll
  for (int j = 0; j < 4; ++j) {
    int row = g * 4 + j;
    float tot = wsum[0][row] + wsum[1][row] + wsum[2][row] + wsum[3][row];
    float sAt = wsumA[0][row] + wsumA[1][row] + wsumA[2][row] + wsumA[3][row];
    float sBt = wsumB[0][row] + wsumB[1][row] + wsumB[2][row] + wsumB[3][row];
    float val = (acc[j] + sAt * t0v + sBt * t128v) / tot;
    int sg = qbase + row;
    vals[((size_t)b * 1024 + sg) * 1024 + h * 64 + dcol] = f2bu(val);
  }
}

// ---------------- output GEMM: out[4096][1024] = vals(bf16) @ owb^T + o_b  (fp32 out)
__global__ __launch_bounds__(256) void gemm_out_k(
    const u16* __restrict__ A, const u16* __restrict__ Bw,
    const float* __restrict__ bias, float* __restrict__ out) {
  __shared__ u16 As[128][40];
  __shared__ u16 Bs[128][40];
  const int tid = threadIdx.x;
  const int l = tid & 63, w = tid >> 6;
  const int wr = w >> 1, wc = w & 1;
  const int fr = l & 15, kq = (l >> 4) * 8;
  const int bid = blockIdx.x;
  const int tn = (bid % 8) * 128, tm = (bid / 8) * 128;
  const int sr = tid >> 1, sc = (tid & 1) * 16;
  const u16* Ag = A + (size_t)(tm + sr) * 1024 + sc;
  const u16* Bg = Bw + (size_t)(tn + sr) * 1024 + sc;
  f32x4 acc[4][4] = {};
  auto compute = [&]() {
    bf16x8 af[4], bfv[4];
#pragma unroll
    for (int mi = 0; mi < 4; ++mi) af[mi] = *(const bf16x8*)&As[wr * 64 + mi * 16 + fr][kq];
#pragma unroll
    for (int ni = 0; ni < 4; ++ni) bfv[ni] = *(const bf16x8*)&Bs[wc * 64 + ni * 16 + fr][kq];
#pragma unroll
    for (int mi = 0; mi < 4; ++mi)
#pragma unroll
      for (int ni = 0; ni < 4; ++ni)
        acc[mi][ni] = mfma16(af[mi], bfv[ni], acc[mi][ni]);
  };
  bf16x8 aX0, aX1, bX0, bX1, aY0, aY1, bY0, bY1;
  aX0 = *(const bf16x8*)(Ag);     aX1 = *(const bf16x8*)(Ag + 8);
  bX0 = *(const bf16x8*)(Bg);     bX1 = *(const bf16x8*)(Bg + 8);
#pragma unroll 1
  for (int kt = 0; kt < 32; kt += 2) {
    __syncthreads();
    *(bf16x8*)&As[sr][sc] = aX0; *(bf16x8*)&As[sr][sc + 8] = aX1;
    *(bf16x8*)&Bs[sr][sc] = bX0; *(bf16x8*)&Bs[sr][sc + 8] = bX1;
    __syncthreads();
    aY0 = *(const bf16x8*)(Ag + (kt + 1) * 32);
    aY1 = *(const bf16x8*)(Ag + (kt + 1) * 32 + 8);
    bY0 = *(const bf16x8*)(Bg + (kt + 1) * 32);
    bY1 = *(const bf16x8*)(Bg + (kt + 1) * 32 + 8);
    compute();
    __syncthreads();
    *(bf16x8*)&As[sr][sc] = aY0; *(bf16x8*)&As[sr][sc + 8] = aY1;
    *(bf16x8*)&Bs[sr][sc] = bY0; *(bf16x8*)&Bs[sr][sc + 8] = bY1;
    __syncthreads();
    if (kt + 2 < 32) {
      aX0 = *(const bf16x8*)(Ag + (kt + 2) * 32);
      aX1 = *(const bf16x8*)(Ag + (kt + 2) * 32 + 8);
      bX0 = *(const bf16x8*)(Bg + (kt + 2) * 32);
      bX1 = *(const bf16x8*)(Bg + (kt + 2) * 32 + 8);
    }
    compute();
  }
#pragma unroll
  for (int mi = 0; mi < 4; ++mi)
#pragma unroll
    for (int ni = 0; ni < 4; ++ni)
#pragma unroll
      for (int j = 0; j < 4; ++j) {
        int gm = tm + wr * 64 + mi * 16 + (l >> 4) * 4 + j;
        int gn = tn + wc * 64 + ni * 16 + fr;
        out[(size_t)gm * 1024 + gn] = acc[mi][ni][j] + bias[gn];
      }
}

extern "C" void kernel_launch(void* const* d_in, const int* in_sizes, int n_in,
                              void* d_out, int out_size, void* d_ws, size_t ws_size,
                              hipStream_t stream) {
  (void)in_sizes; (void)n_in; (void)out_size; (void)ws_size;
  const float* x    = (const float*)d_in[0];
  const float* qkvw = (const float*)d_in[1];
  const float* qkvb = (const float*)d_in[2];
  const float* ow   = (const float*)d_in[3];
  const float* ob   = (const float*)d_in[4];
  const float* tbl  = (const float*)d_in[5];
  const int*   mask = (const int*)d_in[6];
  float* out = (float*)d_out;
  char* ws = (char*)d_ws;
  u16* tb   = (u16*)(ws);
  u16* tbT  = (u16*)(ws + 20480);
  u16* qb   = (u16*)(ws + 40960);
  u16* kb   = (u16*)(ws + 40960 + 8388608ull);
  u16* vt   = (u16*)(ws + 40960 + 2ull * 8388608ull);
  u16* xbvals = (u16*)(ws + 40960 + 3ull * 8388608ull);   // xb (pre-attn) / vals (post)
  u16* bmq  = (u16*)(ws + 40960 + 4ull * 8388608ull);
  u16* wb   = (u16*)(ws + 40960 + 4ull * 8388608ull + 524288ull);
  u16* owb  = (u16*)(ws + 40960 + 4ull * 8388608ull + 524288ull + 6291456ull);

  prep_table_k<<<dim3(1), dim3(256), 0, stream>>>(tbl, tb, tbT);
  prep_maskq_k<<<dim3(1024), dim3(256), 0, stream>>>(mask, bmq);
  prep_bf16_k<<<dim3(2048), dim3(256), 0, stream>>>(x, xbvals, 4194304);
  prep_bf16_k<<<dim3(1536), dim3(256), 0, stream>>>(qkvw, wb, 3145728);
  prep_bf16_k<<<dim3(512), dim3(256), 0, stream>>>(ow, owb, 1048576);
  gemm_qkv_k<<<dim3(768), dim3(256), 0, stream>>>(xbvals, wb, qkvb, qb, kb, vt);
  attn_k<<<dim3(4096), dim3(256), 0, stream>>>(qb, kb, vt, tb, tbT, bmq, xbvals);
  gemm_out_k<<<dim3(256), dim3(256), 0, stream>>>(xbvals, owb, ob, out);
}

// Round 10
// 241.609 us; speedup vs baseline: 1.1516x; 1.1516x over previous
//
#include <hip/hip_runtime.h>

typedef unsigned short u16;
typedef __attribute__((ext_vector_type(8))) short bf16x8;
typedef __attribute__((ext_vector_type(4))) float f32x4;

__device__ __forceinline__ u16 f2bu(float f) {
  union { float f; unsigned u; } v; v.f = f;
  unsigned r = v.u + 0x7fffu + ((v.u >> 16) & 1u);
  return (u16)(r >> 16);
}
__device__ __forceinline__ u16 f2bu_fast(float f) {   // round-half-up, 2 ops
  union { float f; unsigned u; } v; v.f = f;
  return (u16)((v.u + 0x8000u) >> 16);
}
__device__ __forceinline__ float b2f(u16 s) {
  union { unsigned u; float f; } v; v.u = ((unsigned)s) << 16;
  return v.f;
}
__device__ __forceinline__ bf16x8 cvt8(float4 a, float4 b) {
  bf16x8 r;
  r[0] = (short)f2bu(a.x); r[1] = (short)f2bu(a.y);
  r[2] = (short)f2bu(a.z); r[3] = (short)f2bu(a.w);
  r[4] = (short)f2bu(b.x); r[5] = (short)f2bu(b.y);
  r[6] = (short)f2bu(b.z); r[7] = (short)f2bu(b.w);
  return r;
}
__device__ __forceinline__ f32x4 mfma16(bf16x8 a, bf16x8 b, f32x4 c) {
  return __builtin_amdgcn_mfma_f32_16x16x32_bf16(a, b, c, 0, 0, 0);
}

// ---------------- merged fp32 -> bf16 converts (x, qkv_w, o_w), 2048 elem/block
__global__ __launch_bounds__(256) void prep_cvt_k(
    const float* __restrict__ x, const float* __restrict__ w,
    const float* __restrict__ o, u16* __restrict__ xb,
    u16* __restrict__ wbo, u16* __restrict__ ob) {
  int bid = blockIdx.x;
  const float* src; u16* dst; int off;
  if (bid < 2048)      { src = x; dst = xb;  off = bid * 2048; }
  else if (bid < 3584) { src = w; dst = wbo; off = (bid - 2048) * 2048; }
  else                 { src = o; dst = ob;  off = (bid - 3584) * 2048; }
  int idx = off + threadIdx.x * 8;
  float4 a = *(const float4*)(src + idx);
  float4 b = *(const float4*)(src + idx + 4);
  *(bf16x8*)(dst + idx) = cvt8(a, b);
}

// ---------------- table prep: bf16 table [160][64] (pad rows zero) + transpose [64][160]
__global__ void prep_table_k(const float* __restrict__ tbl,
                             u16* __restrict__ tb, u16* __restrict__ tbT) {
  int t = threadIdx.x;
  for (int idx = t; idx < 160 * 64; idx += 256) {
    int r = idx >> 6, d = idx & 63;
    float v = (r < 129) ? tbl[r * 64 + d] : 0.f;
    u16 bv = f2bu(v);
    tb[r * 64 + d] = bv;
    tbT[d * 160 + r] = bv;
  }
}

// ---------------- mask prep: int32 [4][1024][1024] -> transposed 16-bit words
// bmq[b][q][wv][fr] bit nt = mask[b][q][wv*256 + nt*16 + fr]
__global__ __launch_bounds__(256) void prep_maskq_k(const int* __restrict__ mask,
                                                    u16* __restrict__ bmq) {
  int t = blockIdx.x * 256 + threadIdx.x;     // 262144 total
  int fr = t & 15, wv = (t >> 4) & 3;
  int q = (t >> 6) & 1023, b = t >> 16;
  const int* mrow = mask + ((size_t)b * 1024 + q) * 1024 + wv * 256 + fr;
  unsigned bits = 0;
#pragma unroll
  for (int nt = 0; nt < 16; ++nt) bits |= (mrow[nt * 16] != 0 ? 1u : 0u) << nt;
  bmq[t] = (u16)bits;
}

// ---------------- QKV GEMM (bf16 in): C[4096][3072] = xb @ wb^T + b, scatter q/k/v
__global__ __launch_bounds__(256) void gemm_qkv_k(
    const u16* __restrict__ A, const u16* __restrict__ Bw,
    const float* __restrict__ bias,
    u16* __restrict__ qb, u16* __restrict__ kb, u16* __restrict__ vt) {
  __shared__ u16 As[128][40];
  __shared__ u16 Bs[128][40];
  const int tid = threadIdx.x;
  const int l = tid & 63, w = tid >> 6;
  const int wr = w >> 1, wc = w & 1;
  const int fr = l & 15, kq = (l >> 4) * 8;
  const int bid = blockIdx.x;
  const int tn = (bid % 24) * 128, tm = (bid / 24) * 128;
  const int sr = tid >> 1, sc = (tid & 1) * 16;
  const u16* Ag = A + (size_t)(tm + sr) * 1024 + sc;
  const u16* Bg = Bw + (size_t)(tn + sr) * 1024 + sc;
  f32x4 acc[4][4] = {};
  auto compute = [&]() {
    bf16x8 af[4], bfv[4];
#pragma unroll
    for (int mi = 0; mi < 4; ++mi) af[mi] = *(const bf16x8*)&As[wr * 64 + mi * 16 + fr][kq];
#pragma unroll
    for (int ni = 0; ni < 4; ++ni) bfv[ni] = *(const bf16x8*)&Bs[wc * 64 + ni * 16 + fr][kq];
#pragma unroll
    for (int mi = 0; mi < 4; ++mi)
#pragma unroll
      for (int ni = 0; ni < 4; ++ni)
        acc[mi][ni] = mfma16(af[mi], bfv[ni], acc[mi][ni]);
  };
  bf16x8 aX0, aX1, bX0, bX1, aY0, aY1, bY0, bY1;
  aX0 = *(const bf16x8*)(Ag);     aX1 = *(const bf16x8*)(Ag + 8);
  bX0 = *(const bf16x8*)(Bg);     bX1 = *(const bf16x8*)(Bg + 8);
#pragma unroll 1
  for (int kt = 0; kt < 32; kt += 2) {
    __syncthreads();
    *(bf16x8*)&As[sr][sc] = aX0; *(bf16x8*)&As[sr][sc + 8] = aX1;
    *(bf16x8*)&Bs[sr][sc] = bX0; *(bf16x8*)&Bs[sr][sc + 8] = bX1;
    __syncthreads();
    aY0 = *(const bf16x8*)(Ag + (kt + 1) * 32);
    aY1 = *(const bf16x8*)(Ag + (kt + 1) * 32 + 8);
    bY0 = *(const bf16x8*)(Bg + (kt + 1) * 32);
    bY1 = *(const bf16x8*)(Bg + (kt + 1) * 32 + 8);
    compute();
    __syncthreads();
    *(bf16x8*)&As[sr][sc] = aY0; *(bf16x8*)&As[sr][sc + 8] = aY1;
    *(bf16x8*)&Bs[sr][sc] = bY0; *(bf16x8*)&Bs[sr][sc + 8] = bY1;
    __syncthreads();
    if (kt + 2 < 32) {
      aX0 = *(const bf16x8*)(Ag + (kt + 2) * 32);
      aX1 = *(const bf16x8*)(Ag + (kt + 2) * 32 + 8);
      bX0 = *(const bf16x8*)(Bg + (kt + 2) * 32);
      bX1 = *(const bf16x8*)(Bg + (kt + 2) * 32 + 8);
    }
    compute();
  }
#pragma unroll
  for (int mi = 0; mi < 4; ++mi)
#pragma unroll
    for (int ni = 0; ni < 4; ++ni)
#pragma unroll
      for (int j = 0; j < 4; ++j) {
        int gm = tm + wr * 64 + mi * 16 + (l >> 4) * 4 + j;
        int gn = tn + wc * 64 + ni * 16 + fr;
        float v = acc[mi][ni][j] + bias[gn];
        int b = gm >> 10, s = gm & 1023;
        unsigned gnu = (unsigned)gn;
        unsigned h = gnu / 192u;
        unsigned rem = gnu - h * 192u;
        unsigned which = rem >> 6, d = rem & 63u;
        int bh = b * 16 + (int)h;
        u16 bv = f2bu(v);
        if (which == 0u)      qb[((size_t)bh * 1024 + s) * 64 + d] = bv;
        else if (which == 1u) kb[((size_t)bh * 1024 + s) * 64 + d] = bv;
        else                  vt[((size_t)bh * 64 + d) * 1024 + s] = bv;
      }
}

// ---------------- attention: SINGLE WAVE per block (64 thr), zero barriers
// 1 block = (b,h,16 q-rows); 128-col chunks through small LDS p-buffer
#define CSTR 136   // row stride u16: 272B = 17 16B slots (odd -> 2-way max)
__global__ __launch_bounds__(64) void attn_k(
    const u16* __restrict__ qb, const u16* __restrict__ kb,
    const u16* __restrict__ vt, const u16* __restrict__ tb,
    const u16* __restrict__ tbT, const u16* __restrict__ bmq,
    u16* __restrict__ vals) {
  __shared__ u16 pc[16 * CSTR];        // p~ chunk (128 cols, bf16)
  __shared__ u16 qr[16 * CSTR];        // qrel bf16 (r = 0..128)
  __shared__ u16 qs[16 * CSTR];        // band region r=1..127 (pre-zeroed)
  const int l = threadIdx.x;
  const int fr = l & 15, g = l >> 4, kq = g * 8;
  const int blk = ((int)blockIdx.x & 7) * 512 + ((int)blockIdx.x >> 3);  // XCD swizzle
  const int qt = blk & 63, bh = blk >> 6;
  const int b = bh >> 4, h = bh & 15;
  const int qbase = qt * 16;
  const u16* qrow = qb + ((size_t)bh * 1024 + qbase) * 64;
  bf16x8 qa0 = *(const bf16x8*)(qrow + fr * 64 + kq);
  bf16x8 qa1 = *(const bf16x8*)(qrow + fr * 64 + 32 + kq);
  const u16* kbase = kb + (size_t)bh * 65536;
  const u16* vbase = vt + (size_t)bh * 65536;
  // zero band buffer: 272 x 8-slots over 64 lanes
#pragma unroll
  for (int i = 0; i < 5; ++i) {
    int s = i * 64 + l;
    if (s < 272) { bf16x8 z = {}; *(bf16x8*)&qs[(s / 17) * CSTR + (s % 17) * 8] = z; }
  }
  // pass 0: qrel[row][r] = q . table[r]  (bf16 into qr); save r=0 / r=128 accs
  f32x4 a_t0 = {}, a_t8 = {};
#pragma unroll
  for (int t = 0; t < 9; ++t) {
    const u16* tp = tb + (t * 16 + fr) * 64 + kq;
    bf16x8 t0 = *(const bf16x8*)(tp);
    bf16x8 t1 = *(const bf16x8*)(tp + 32);
    f32x4 a = {0.f, 0.f, 0.f, 0.f};
    a = mfma16(qa0, t0, a);
    a = mfma16(qa1, t1, a);
    int rg = t * 16 + fr;
    if (rg < 129) {
#pragma unroll
      for (int j = 0; j < 4; ++j) qr[(g * 4 + j) * CSTR + rg] = f2bu(a[j]);
    }
    if (t == 0) a_t0 = a;
    if (t == 8) a_t8 = a;
  }
  float q0r[4], q128r[4];
#pragma unroll
  for (int j = 0; j < 4; ++j) {
    q0r[j] = __shfl(a_t0[j], l & 48);     // lane fr==0 of this group holds r=0
    q128r[j] = __shfl(a_t8[j], l & 48);   // and r=128
  }
  // mask words
  unsigned bmX[4], bmY[4];
  auto ldM = [&](int wv, unsigned* d) {
#pragma unroll
    for (int j = 0; j < 4; ++j)
      d[j] = bmq[(((size_t)b * 1024 + qbase + g * 4 + j) * 4 + wv) * 16 + fr];
  };
  ldM(0, bmX);
  const float C1 = 0.18033688011112042f;   // 0.125*log2(e)
  const float C2 = 17.31234049066756f;     // 12*log2(e)
  float ps[4] = {0.f, 0.f, 0.f, 0.f};
  float psA[4] = {0.f, 0.f, 0.f, 0.f};
  float psB[4] = {0.f, 0.f, 0.f, 0.f};
  f32x4 acc[4] = {};                       // PV accumulators, one per d-group
  auto ldK = [&](int tt, bf16x8& lo, bf16x8& hi) {
    const u16* kp = kbase + (size_t)(tt * 16 + fr) * 64 + kq;
    lo = *(const bf16x8*)(kp);
    hi = *(const bf16x8*)(kp + 32);
  };
  // QK tile: tt in 0..63; epilogue includes inline band store (mixed tiles only)
  auto tileC = [&](int tt, bf16x8 k0, bf16x8 k1) {
    int ncol = tt * 16;
    int kgl = ncol + fr;
    int lcol = (tt & 7) * 16 + fr;
    int bsh = tt & 15;
    f32x4 a = {0.f, 0.f, 0.f, 0.f};
    a = mfma16(qa0, k0, a);
    a = mfma16(qa1, k1, a);
    if (ncol + 79 <= qbase) {              // whole tile: rdx = 0, no band
#pragma unroll
      for (int j = 0; j < 4; ++j) {
        float s = a[j] + q0r[j];
        float arg = ((bmX[j] >> bsh) & 1u) ? __builtin_fmaf(s, C1, -C2) : -1e30f;
        float e = __builtin_amdgcn_exp2f(arg);
        ps[j] += e; psA[j] += e;
        pc[(g * 4 + j) * CSTR + lcol] = f2bu_fast(e);
      }
    } else if (ncol >= qbase + 79) {       // whole tile: rdx = 128, no band
#pragma unroll
      for (int j = 0; j < 4; ++j) {
        float s = a[j] + q128r[j];
        float arg = ((bmX[j] >> bsh) & 1u) ? __builtin_fmaf(s, C1, -C2) : -1e30f;
        float e = __builtin_amdgcn_exp2f(arg);
        ps[j] += e; psB[j] += e;
        pc[(g * 4 + j) * CSTR + lcol] = f2bu_fast(e);
      }
    } else {                                // mixed tile: per-element rdx + band store
#pragma unroll
      for (int j = 0; j < 4; ++j) {
        int row = g * 4 + j;
        int q = qbase + row;
        int dd = kgl - q;
        int rdx = dd < -64 ? 0 : (dd > 64 ? 128 : dd + 64);
        bool ov = (q >= 1 && q <= 1022);
        bool edge = ov && (kgl == 0 || kgl == 1023);
        if (edge) rdx = (kgl == 0) ? 0 : 128;
        float s = a[j] + b2f(qr[row * CSTR + rdx]);
        float arg = ((bmX[j] >> bsh) & 1u) ? __builtin_fmaf(s, C1, -C2) : -1e30f;
        float e = __builtin_amdgcn_exp2f(arg);
        ps[j] += e;
        psA[j] += (rdx == 0) ? e : 0.f;
        psB[j] += (rdx == 128) ? e : 0.f;
        u16 pe = f2bu_fast(e);
        pc[row * CSTR + lcol] = pe;
        int r = dd + 64;
        if (r >= 1 && r <= 127 && !edge) qs[row * CSTR + r] = pe;
      }
    }
  };
  bf16x8 xa0, xa1, ya0, ya1;
  ldK(0, xa0, xa1); ldK(1, ya0, ya1);
#pragma unroll 1
  for (int c = 0; c < 8; ++c) {
    if ((c & 1) == 0 && c > 0) {
#pragma unroll
      for (int j = 0; j < 4; ++j) bmX[j] = bmY[j];
    }
    if ((c & 1) == 1 && c < 7) ldM((c + 1) >> 1, bmY);
    // QK: 8 tiles, depth-2 prefetch
#pragma unroll
    for (int t = 0; t < 8; t += 2) {
      int tt = c * 8 + t;
      bf16x8 na0, na1, nb0, nb1;
      bool pf = (tt + 3 < 64);
      if (pf) { ldK(tt + 2, na0, na1); ldK(tt + 3, nb0, nb1); }
      tileC(tt, xa0, xa1);
      tileC(tt + 1, ya0, ya1);
      if (pf) { xa0 = na0; xa1 = na1; ya0 = nb0; ya1 = nb1; }
    }
    // PV partial: 4 d-groups x 4 MFMA over this 128-col chunk
    const u16* ar = pc + fr * CSTR + kq;
#pragma unroll
    for (int dg = 0; dg < 4; ++dg) {
      const u16* vr = vbase + (size_t)(dg * 16 + fr) * 1024 + c * 128 + kq;
      bf16x8 v0 = *(const bf16x8*)(vr);
      bf16x8 v1 = *(const bf16x8*)(vr + 32);
      bf16x8 v2 = *(const bf16x8*)(vr + 64);
      bf16x8 v3 = *(const bf16x8*)(vr + 96);
      acc[dg] = mfma16(*(const bf16x8*)(ar), v0, acc[dg]);
      acc[dg] = mfma16(*(const bf16x8*)(ar + 32), v1, acc[dg]);
      acc[dg] = mfma16(*(const bf16x8*)(ar + 64), v2, acc[dg]);
      acc[dg] = mfma16(*(const bf16x8*)(ar + 96), v3, acc[dg]);
    }
  }
  // reduce row sums within 16-lane groups (all lanes end with totals)
#pragma unroll
  for (int j = 0; j < 4; ++j) {
#pragma unroll
    for (int off = 1; off <= 8; off <<= 1) {
      ps[j] += __shfl_xor(ps[j], off);
      psA[j] += __shfl_xor(psA[j], off);
      psB[j] += __shfl_xor(psB[j], off);
    }
  }
  // band MFMAs + rank-1 r=0/128 + normalize + store
  const u16* srow = qs + fr * CSTR + kq;
  bf16x8 sa0 = *(const bf16x8*)(srow);
  bf16x8 sa1 = *(const bf16x8*)(srow + 32);
  bf16x8 sa2 = *(const bf16x8*)(srow + 64);
  bf16x8 sa3 = *(const bf16x8*)(srow + 96);
#pragma unroll
  for (int dg = 0; dg < 4; ++dg) {
    int dc = dg * 16 + fr;
    const u16* tq = tbT + dc * 160 + kq;
    f32x4 av = acc[dg];
    av = mfma16(sa0, *(const bf16x8*)(tq), av);
    av = mfma16(sa1, *(const bf16x8*)(tq + 32), av);
    av = mfma16(sa2, *(const bf16x8*)(tq + 64), av);
    av = mfma16(sa3, *(const bf16x8*)(tq + 96), av);
    float t0v = b2f(tb[dc]);
    float t128v = b2f(tb[128 * 64 + dc]);
#pragma unroll
    for (int j = 0; j < 4; ++j) {
      float val = (av[j] + psA[j] * t0v + psB[j] * t128v) / ps[j];
      int sg = qbase + g * 4 + j;
      vals[((size_t)b * 1024 + sg) * 1024 + h * 64 + dc] = f2bu(val);
    }
  }
}

// ---------------- output GEMM: out[4096][1024] = vals(bf16) @ owb^T + o_b  (fp32 out)
__global__ __launch_bounds__(256) void gemm_out_k(
    const u16* __restrict__ A, const u16* __restrict__ Bw,
    const float* __restrict__ bias, float* __restrict__ out) {
  __shared__ u16 As[128][40];
  __shared__ u16 Bs[128][40];
  const int tid = threadIdx.x;
  const int l = tid & 63, w = tid >> 6;
  const int wr = w >> 1, wc = w & 1;
  const int fr = l & 15, kq = (l >> 4) * 8;
  const int bid = blockIdx.x;
  const int tn = (bid % 8) * 128, tm = (bid / 8) * 128;
  const int sr = tid >> 1, sc = (tid & 1) * 16;
  const u16* Ag = A + (size_t)(tm + sr) * 1024 + sc;
  const u16* Bg = Bw + (size_t)(tn + sr) * 1024 + sc;
  f32x4 acc[4][4] = {};
  auto compute = [&]() {
    bf16x8 af[4], bfv[4];
#pragma unroll
    for (int mi = 0; mi < 4; ++mi) af[mi] = *(const bf16x8*)&As[wr * 64 + mi * 16 + fr][kq];
#pragma unroll
    for (int ni = 0; ni < 4; ++ni) bfv[ni] = *(const bf16x8*)&Bs[wc * 64 + ni * 16 + fr][kq];
#pragma unroll
    for (int mi = 0; mi < 4; ++mi)
#pragma unroll
      for (int ni = 0; ni < 4; ++ni)
        acc[mi][ni] = mfma16(af[mi], bfv[ni], acc[mi][ni]);
  };
  bf16x8 aX0, aX1, bX0, bX1, aY0, aY1, bY0, bY1;
  aX0 = *(const bf16x8*)(Ag);     aX1 = *(const bf16x8*)(Ag + 8);
  bX0 = *(const bf16x8*)(Bg);     bX1 = *(const bf16x8*)(Bg + 8);
#pragma unroll 1
  for (int kt = 0; kt < 32; kt += 2) {
    __syncthreads();
    *(bf16x8*)&As[sr][sc] = aX0; *(bf16x8*)&As[sr][sc + 8] = aX1;
    *(bf16x8*)&Bs[sr][sc] = bX0; *(bf16x8*)&Bs[sr][sc + 8] = bX1;
    __syncthreads();
    aY0 = *(const bf16x8*)(Ag + (kt + 1) * 32);
    aY1 = *(const bf16x8*)(Ag + (kt + 1) * 32 + 8);
    bY0 = *(const bf16x8*)(Bg + (kt + 1) * 32);
    bY1 = *(const bf16x8*)(Bg + (kt + 1) * 32 + 8);
    compute();
    __syncthreads();
    *(bf16x8*)&As[sr][sc] = aY0; *(bf16x8*)&As[sr][sc + 8] = aY1;
    *(bf16x8*)&Bs[sr][sc] = bY0; *(bf16x8*)&Bs[sr][sc + 8] = bY1;
    __syncthreads();
    if (kt + 2 < 32) {
      aX0 = *(const bf16x8*)(Ag + (kt + 2) * 32);
      aX1 = *(const bf16x8*)(Ag + (kt + 2) * 32 + 8);
      bX0 = *(const bf16x8*)(Bg + (kt + 2) * 32);
      bX1 = *(const bf16x8*)(Bg + (kt + 2) * 32 + 8);
    }
    compute();
  }
#pragma unroll
  for (int mi = 0; mi < 4; ++mi)
#pragma unroll
    for (int ni = 0; ni < 4; ++ni)
#pragma unroll
      for (int j = 0; j < 4; ++j) {
        int gm = tm + wr * 64 + mi * 16 + (l >> 4) * 4 + j;
        int gn = tn + wc * 64 + ni * 16 + fr;
        out[(size_t)gm * 1024 + gn] = acc[mi][ni][j] + bias[gn];
      }
}

extern "C" void kernel_launch(void* const* d_in, const int* in_sizes, int n_in,
                              void* d_out, int out_size, void* d_ws, size_t ws_size,
                              hipStream_t stream) {
  (void)in_sizes; (void)n_in; (void)out_size; (void)ws_size;
  const float* x    = (const float*)d_in[0];
  const float* qkvw = (const float*)d_in[1];
  const float* qkvb = (const float*)d_in[2];
  const float* ow   = (const float*)d_in[3];
  const float* ob   = (const float*)d_in[4];
  const float* tbl  = (const float*)d_in[5];
  const int*   mask = (const int*)d_in[6];
  float* out = (float*)d_out;
  char* ws = (char*)d_ws;
  u16* tb   = (u16*)(ws);
  u16* tbT  = (u16*)(ws + 20480);
  u16* qb   = (u16*)(ws + 40960);
  u16* kb   = (u16*)(ws + 40960 + 8388608ull);
  u16* vt   = (u16*)(ws + 40960 + 2ull * 8388608ull);
  u16* xbvals = (u16*)(ws + 40960 + 3ull * 8388608ull);   // xb (pre-attn) / vals (post)
  u16* bmq  = (u16*)(ws + 40960 + 4ull * 8388608ull);
  u16* wb   = (u16*)(ws + 40960 + 4ull * 8388608ull + 524288ull);
  u16* owb  = (u16*)(ws + 40960 + 4ull * 8388608ull + 524288ull + 6291456ull);

  prep_table_k<<<dim3(1), dim3(256), 0, stream>>>(tbl, tb, tbT);
  prep_maskq_k<<<dim3(1024), dim3(256), 0, stream>>>(mask, bmq);
  prep_cvt_k<<<dim3(4096), dim3(256), 0, stream>>>(x, qkvw, ow, xbvals, wb, owb);
  gemm_qkv_k<<<dim3(768), dim3(256), 0, stream>>>(xbvals, wb, qkvb, qb, kb, vt);
  attn_k<<<dim3(4096), dim3(64), 0, stream>>>(qb, kb, vt, tb, tbT, bmq, xbvals);
  gemm_out_k<<<dim3(256), dim3(256), 0, stream>>>(xbvals, owb, ob, out);
}

// Round 11
// 184.429 us; speedup vs baseline: 1.5086x; 1.3100x over previous
//
#include <hip/hip_runtime.h>

typedef unsigned short u16;
typedef __attribute__((ext_vector_type(8))) short bf16x8;
typedef __attribute__((ext_vector_type(4))) float f32x4;

__device__ __forceinline__ u16 f2bu(float f) {
  union { float f; unsigned u; } v; v.f = f;
  unsigned r = v.u + 0x7fffu + ((v.u >> 16) & 1u);
  return (u16)(r >> 16);
}
__device__ __forceinline__ u16 f2bu_fast(float f) {   // round-half-up, 2 ops
  union { float f; unsigned u; } v; v.f = f;
  return (u16)((v.u + 0x8000u) >> 16);
}
__device__ __forceinline__ float b2f(u16 s) {
  union { unsigned u; float f; } v; v.u = ((unsigned)s) << 16;
  return v.f;
}
__device__ __forceinline__ bf16x8 cvt8(float4 a, float4 b) {
  bf16x8 r;
  r[0] = (short)f2bu(a.x); r[1] = (short)f2bu(a.y);
  r[2] = (short)f2bu(a.z); r[3] = (short)f2bu(a.w);
  r[4] = (short)f2bu(b.x); r[5] = (short)f2bu(b.y);
  r[6] = (short)f2bu(b.z); r[7] = (short)f2bu(b.w);
  return r;
}
__device__ __forceinline__ f32x4 mfma16(bf16x8 a, bf16x8 b, f32x4 c) {
  return __builtin_amdgcn_mfma_f32_16x16x32_bf16(a, b, c, 0, 0, 0);
}

// ---------------- merged fp32 -> bf16 converts (x, qkv_w, o_w), 2048 elem/block
__global__ __launch_bounds__(256) void prep_cvt_k(
    const float* __restrict__ x, const float* __restrict__ w,
    const float* __restrict__ o, u16* __restrict__ xb,
    u16* __restrict__ wbo, u16* __restrict__ ob) {
  int bid = blockIdx.x;
  const float* src; u16* dst; int off;
  if (bid < 2048)      { src = x; dst = xb;  off = bid * 2048; }
  else if (bid < 3584) { src = w; dst = wbo; off = (bid - 2048) * 2048; }
  else                 { src = o; dst = ob;  off = (bid - 3584) * 2048; }
  int idx = off + threadIdx.x * 8;
  float4 a = *(const float4*)(src + idx);
  float4 b = *(const float4*)(src + idx + 4);
  *(bf16x8*)(dst + idx) = cvt8(a, b);
}

// ---------------- table prep: bf16 table [160][64] (pad rows zero) + transpose [64][160]
__global__ void prep_table_k(const float* __restrict__ tbl,
                             u16* __restrict__ tb, u16* __restrict__ tbT) {
  int t = threadIdx.x;
  for (int idx = t; idx < 160 * 64; idx += 256) {
    int r = idx >> 6, d = idx & 63;
    float v = (r < 129) ? tbl[r * 64 + d] : 0.f;
    u16 bv = f2bu(v);
    tb[r * 64 + d] = bv;
    tbT[d * 160 + r] = bv;
  }
}

// ---------------- mask prep: int32 [4][1024][1024] -> transposed 16-bit words
// bmq[b][q][wv][fr] bit nt = mask[b][q][wv*256 + nt*16 + fr]
__global__ __launch_bounds__(256) void prep_maskq_k(const int* __restrict__ mask,
                                                    u16* __restrict__ bmq) {
  int t = blockIdx.x * 256 + threadIdx.x;     // 262144 total
  int fr = t & 15, wv = (t >> 4) & 3;
  int q = (t >> 6) & 1023, b = t >> 16;
  const int* mrow = mask + ((size_t)b * 1024 + q) * 1024 + wv * 256 + fr;
  unsigned bits = 0;
#pragma unroll
  for (int nt = 0; nt < 16; ++nt) bits |= (mrow[nt * 16] != 0 ? 1u : 0u) << nt;
  bmq[t] = (u16)bits;
}

// ---------------- QKV GEMM (bf16 in): C[4096][3072] = xb @ wb^T + b, scatter q/k/v
__global__ __launch_bounds__(256) void gemm_qkv_k(
    const u16* __restrict__ A, const u16* __restrict__ Bw,
    const float* __restrict__ bias,
    u16* __restrict__ qb, u16* __restrict__ kb, u16* __restrict__ vt) {
  __shared__ u16 As[128][40];
  __shared__ u16 Bs[128][40];
  const int tid = threadIdx.x;
  const int l = tid & 63, w = tid >> 6;
  const int wr = w >> 1, wc = w & 1;
  const int fr = l & 15, kq = (l >> 4) * 8;
  const int bid = blockIdx.x;
  const int tn = (bid % 24) * 128, tm = (bid / 24) * 128;
  const int sr = tid >> 1, sc = (tid & 1) * 16;
  const u16* Ag = A + (size_t)(tm + sr) * 1024 + sc;
  const u16* Bg = Bw + (size_t)(tn + sr) * 1024 + sc;
  f32x4 acc[4][4] = {};
  auto compute = [&]() {
    bf16x8 af[4], bfv[4];
#pragma unroll
    for (int mi = 0; mi < 4; ++mi) af[mi] = *(const bf16x8*)&As[wr * 64 + mi * 16 + fr][kq];
#pragma unroll
    for (int ni = 0; ni < 4; ++ni) bfv[ni] = *(const bf16x8*)&Bs[wc * 64 + ni * 16 + fr][kq];
#pragma unroll
    for (int mi = 0; mi < 4; ++mi)
#pragma unroll
      for (int ni = 0; ni < 4; ++ni)
        acc[mi][ni] = mfma16(af[mi], bfv[ni], acc[mi][ni]);
  };
  bf16x8 aX0, aX1, bX0, bX1, aY0, aY1, bY0, bY1;
  aX0 = *(const bf16x8*)(Ag);     aX1 = *(const bf16x8*)(Ag + 8);
  bX0 = *(const bf16x8*)(Bg);     bX1 = *(const bf16x8*)(Bg + 8);
#pragma unroll 1
  for (int kt = 0; kt < 32; kt += 2) {
    __syncthreads();
    *(bf16x8*)&As[sr][sc] = aX0; *(bf16x8*)&As[sr][sc + 8] = aX1;
    *(bf16x8*)&Bs[sr][sc] = bX0; *(bf16x8*)&Bs[sr][sc + 8] = bX1;
    __syncthreads();
    aY0 = *(const bf16x8*)(Ag + (kt + 1) * 32);
    aY1 = *(const bf16x8*)(Ag + (kt + 1) * 32 + 8);
    bY0 = *(const bf16x8*)(Bg + (kt + 1) * 32);
    bY1 = *(const bf16x8*)(Bg + (kt + 1) * 32 + 8);
    compute();
    __syncthreads();
    *(bf16x8*)&As[sr][sc] = aY0; *(bf16x8*)&As[sr][sc + 8] = aY1;
    *(bf16x8*)&Bs[sr][sc] = bY0; *(bf16x8*)&Bs[sr][sc + 8] = bY1;
    __syncthreads();
    if (kt + 2 < 32) {
      aX0 = *(const bf16x8*)(Ag + (kt + 2) * 32);
      aX1 = *(const bf16x8*)(Ag + (kt + 2) * 32 + 8);
      bX0 = *(const bf16x8*)(Bg + (kt + 2) * 32);
      bX1 = *(const bf16x8*)(Bg + (kt + 2) * 32 + 8);
    }
    compute();
  }
#pragma unroll
  for (int mi = 0; mi < 4; ++mi)
#pragma unroll
    for (int ni = 0; ni < 4; ++ni)
#pragma unroll
      for (int j = 0; j < 4; ++j) {
        int gm = tm + wr * 64 + mi * 16 + (l >> 4) * 4 + j;
        int gn = tn + wc * 64 + ni * 16 + fr;
        float v = acc[mi][ni][j] + bias[gn];
        int b = gm >> 10, s = gm & 1023;
        unsigned gnu = (unsigned)gn;
        unsigned h = gnu / 192u;
        unsigned rem = gnu - h * 192u;
        unsigned which = rem >> 6, d = rem & 63u;
        int bh = b * 16 + (int)h;
        u16 bv = f2bu(v);
        if (which == 0u)      qb[((size_t)bh * 1024 + s) * 64 + d] = bv;
        else if (which == 1u) kb[((size_t)bh * 1024 + s) * 64 + d] = bv;
        else                  vt[((size_t)bh * 64 + d) * 1024 + s] = bv;
      }
}

// ---------------- attention: block = (bh, 64 q-rows), 4 waves; K/V LDS-staged+shared
// chunks of 64 k-cols; XOR-swizzled K/V; per-wave p/qrel/band (no cross-wave data)
#define PCW 72     // p row stride u16 (144B = 9 slots, odd)
#define QRS 132    // qrel row stride u16 (scalar access only)
#define QSS 136    // band row stride u16 (272B = 17 slots, odd)
__global__ __launch_bounds__(256) void attn_k(
    const u16* __restrict__ qb, const u16* __restrict__ kb,
    const u16* __restrict__ vt, const u16* __restrict__ tb,
    const u16* __restrict__ tbT, const u16* __restrict__ bmq,
    u16* __restrict__ vals) {
  __shared__ u16 Kbuf[64 * 64];        // 8 KB: K chunk [64 k][64 d], slot^=(k&7)
  __shared__ u16 Vbuf[64 * 64];        // 8 KB: V^T chunk [64 d][64 k], slot^=(d&7)
  __shared__ u16 pcb[4][16 * PCW];     // 9 KB: per-wave p~ chunk
  __shared__ u16 qr[64 * QRS];         // 16.5 KB: qrel (per-wave rows)
  __shared__ u16 qs[64 * QSS];         // 17 KB: band region (per-wave rows)
  const int tid = threadIdx.x;
  const int l = tid & 63, w = tid >> 6;
  const int fr = l & 15, g = l >> 4, kq = g * 8;
  const int blk = ((int)blockIdx.x & 7) * 128 + ((int)blockIdx.x >> 3);  // XCD swizzle
  const int qt = blk & 15, bh = blk >> 4;
  const int b = bh >> 4, h = bh & 15;
  const int qbase = qt * 64 + w * 16;            // this wave's q-row base
  const u16* kbase = kb + (size_t)bh * 65536;
  const u16* vbase = vt + (size_t)bh * 65536;
  u16* pcw = &pcb[w][0];
  // staging regs + loaders (cooperative across all 256 threads)
  const int srow0 = tid >> 3, sslot = tid & 7;
  bf16x8 sK0, sK1, sV0, sV1;
  auto ldStage = [&](int c) {
    const u16* ks = kbase + (size_t)(c * 64) * 64;
    sK0 = *(const bf16x8*)(ks + srow0 * 64 + sslot * 8);
    sK1 = *(const bf16x8*)(ks + (srow0 + 32) * 64 + sslot * 8);
    const u16* vs = vbase + c * 64 + sslot * 8;
    sV0 = *(const bf16x8*)(vs + (size_t)srow0 * 1024);
    sV1 = *(const bf16x8*)(vs + (size_t)(srow0 + 32) * 1024);
  };
  ldStage(0);                                    // issue chunk-0 loads early
  // Q fragments
  const u16* qrow = qb + ((size_t)bh * 1024 + qbase) * 64;
  bf16x8 qa0 = *(const bf16x8*)(qrow + fr * 64 + kq);
  bf16x8 qa1 = *(const bf16x8*)(qrow + fr * 64 + 32 + kq);
  // zero band buffer (each thread clears block-shared region cooperatively)
  for (int i = tid; i < 64 * 17; i += 256) {
    bf16x8 z = {};
    *(bf16x8*)&qs[(i / 17) * QSS + (i % 17) * 8] = z;
  }
  // pass 0: qrel for this wave's 16 rows
  f32x4 a_t0 = {}, a_t8 = {};
#pragma unroll
  for (int t = 0; t < 9; ++t) {
    const u16* tp = tb + (t * 16 + fr) * 64 + kq;
    bf16x8 t0 = *(const bf16x8*)(tp);
    bf16x8 t1 = *(const bf16x8*)(tp + 32);
    f32x4 a = {0.f, 0.f, 0.f, 0.f};
    a = mfma16(qa0, t0, a);
    a = mfma16(qa1, t1, a);
    int rg = t * 16 + fr;
    if (rg < 129) {
#pragma unroll
      for (int j = 0; j < 4; ++j) qr[(w * 16 + g * 4 + j) * QRS + rg] = f2bu(a[j]);
    }
    if (t == 0) a_t0 = a;
    if (t == 8) a_t8 = a;
  }
  float q0r[4], q128r[4];
#pragma unroll
  for (int j = 0; j < 4; ++j) {
    q0r[j] = __shfl(a_t0[j], l & 48);
    q128r[j] = __shfl(a_t8[j], l & 48);
  }
  // mask words for current 256-col window
  unsigned bm[4];
  auto ldM = [&](int wv) {
#pragma unroll
    for (int j = 0; j < 4; ++j)
      bm[j] = bmq[(((size_t)b * 1024 + qbase + g * 4 + j) * 4 + wv) * 16 + fr];
  };
  const float C1 = 0.18033688011112042f;   // 0.125*log2(e)
  const float C2 = 17.31234049066756f;     // 12*log2(e)
  float ps[4] = {0.f, 0.f, 0.f, 0.f};
  float psA[4] = {0.f, 0.f, 0.f, 0.f};
  float psB[4] = {0.f, 0.f, 0.f, 0.f};
  f32x4 acc[4] = {};
  auto kfrag = [&](int t2, int hh) -> bf16x8 {
    int rk = t2 * 16 + fr;
    int sl = (g + 4 * hh) ^ (rk & 7);
    return *(const bf16x8*)&Kbuf[rk * 64 + sl * 8];
  };
  auto vfrag = [&](int dg, int i) -> bf16x8 {
    int rv = dg * 16 + fr;
    int sl = (g + 4 * i) ^ (rv & 7);
    return *(const bf16x8*)&Vbuf[rv * 64 + sl * 8];
  };
#pragma unroll 1
  for (int c = 0; c < 16; ++c) {
    __syncthreads();                     // all waves done reading prev chunk bufs
    {                                    // write staged chunk c (waits its vmcnt)
      *(bf16x8*)&Kbuf[srow0 * 64 + (sslot ^ (srow0 & 7)) * 8] = sK0;
      *(bf16x8*)&Kbuf[(srow0 + 32) * 64 + (sslot ^ ((srow0 + 32) & 7)) * 8] = sK1;
      *(bf16x8*)&Vbuf[srow0 * 64 + (sslot ^ (srow0 & 7)) * 8] = sV0;
      *(bf16x8*)&Vbuf[(srow0 + 32) * 64 + (sslot ^ ((srow0 + 32) & 7)) * 8] = sV1;
    }
    __syncthreads();                     // bufs ready
    if (c < 15) ldStage(c + 1);          // issue next chunk loads (hidden by compute)
    if ((c & 3) == 0) ldM(c >> 2);
    // QK: 4 tiles of 16 cols
#pragma unroll
    for (int t2 = 0; t2 < 4; ++t2) {
      int tt = c * 4 + t2;
      int ncol = tt * 16;
      int kgl = ncol + fr;
      int lcol = t2 * 16 + fr;
      int bsh = tt & 15;
      f32x4 a = {0.f, 0.f, 0.f, 0.f};
      a = mfma16(qa0, kfrag(t2, 0), a);
      a = mfma16(qa1, kfrag(t2, 1), a);
      if (ncol + 79 <= qbase) {          // whole tile: rdx = 0
#pragma unroll
        for (int j = 0; j < 4; ++j) {
          float s = a[j] + q0r[j];
          float arg = ((bm[j] >> bsh) & 1u) ? __builtin_fmaf(s, C1, -C2) : -1e30f;
          float e = __builtin_amdgcn_exp2f(arg);
          ps[j] += e; psA[j] += e;
          pcw[(g * 4 + j) * PCW + lcol] = f2bu_fast(e);
        }
      } else if (ncol >= qbase + 79) {   // whole tile: rdx = 128
#pragma unroll
        for (int j = 0; j < 4; ++j) {
          float s = a[j] + q128r[j];
          float arg = ((bm[j] >> bsh) & 1u) ? __builtin_fmaf(s, C1, -C2) : -1e30f;
          float e = __builtin_amdgcn_exp2f(arg);
          ps[j] += e; psB[j] += e;
          pcw[(g * 4 + j) * PCW + lcol] = f2bu_fast(e);
        }
      } else {                            // mixed tile: per-element rdx + band store
#pragma unroll
        for (int j = 0; j < 4; ++j) {
          int row = g * 4 + j;
          int q = qbase + row;
          int dd = kgl - q;
          int rdx = dd < -64 ? 0 : (dd > 64 ? 128 : dd + 64);
          bool ov = (q >= 1 && q <= 1022);
          bool edge = ov && (kgl == 0 || kgl == 1023);
          if (edge) rdx = (kgl == 0) ? 0 : 128;
          float s = a[j] + b2f(qr[(w * 16 + row) * QRS + rdx]);
          float arg = ((bm[j] >> bsh) & 1u) ? __builtin_fmaf(s, C1, -C2) : -1e30f;
          float e = __builtin_amdgcn_exp2f(arg);
          ps[j] += e;
          psA[j] += (rdx == 0) ? e : 0.f;
          psB[j] += (rdx == 128) ? e : 0.f;
          u16 pe = f2bu_fast(e);
          pcw[row * PCW + lcol] = pe;
          int r = dd + 64;
          if (r >= 1 && r <= 127 && !edge) qs[(w * 16 + row) * QSS + r] = pe;
        }
      }
    }
    // PV partial over this 64-k chunk: 4 d-groups x 2 MFMA
    {
      const u16* prow = pcw + fr * PCW + kq;
      bf16x8 p0 = *(const bf16x8*)(prow);
      bf16x8 p1 = *(const bf16x8*)(prow + 32);
#pragma unroll
      for (int dg = 0; dg < 4; ++dg) {
        acc[dg] = mfma16(p0, vfrag(dg, 0), acc[dg]);
        acc[dg] = mfma16(p1, vfrag(dg, 1), acc[dg]);
      }
    }
  }
  // reduce row sums within 16-lane groups
#pragma unroll
  for (int j = 0; j < 4; ++j) {
#pragma unroll
    for (int off = 1; off <= 8; off <<= 1) {
      ps[j] += __shfl_xor(ps[j], off);
      psA[j] += __shfl_xor(psA[j], off);
      psB[j] += __shfl_xor(psB[j], off);
    }
  }
  // band MFMAs + rank-1 r=0/128 + normalize + store
  const u16* srow = qs + (w * 16 + fr) * QSS + kq;
  bf16x8 sa0 = *(const bf16x8*)(srow);
  bf16x8 sa1 = *(const bf16x8*)(srow + 32);
  bf16x8 sa2 = *(const bf16x8*)(srow + 64);
  bf16x8 sa3 = *(const bf16x8*)(srow + 96);
#pragma unroll
  for (int dg = 0; dg < 4; ++dg) {
    int dc = dg * 16 + fr;
    const u16* tq = tbT + dc * 160 + kq;
    f32x4 av = acc[dg];
    av = mfma16(sa0, *(const bf16x8*)(tq), av);
    av = mfma16(sa1, *(const bf16x8*)(tq + 32), av);
    av = mfma16(sa2, *(const bf16x8*)(tq + 64), av);
    av = mfma16(sa3, *(const bf16x8*)(tq + 96), av);
    float t0v = b2f(tb[dc]);
    float t128v = b2f(tb[128 * 64 + dc]);
#pragma unroll
    for (int j = 0; j < 4; ++j) {
      float val = (av[j] + psA[j] * t0v + psB[j] * t128v) / ps[j];
      int sg = qbase + g * 4 + j;
      vals[((size_t)b * 1024 + sg) * 1024 + h * 64 + dc] = f2bu(val);
    }
  }
}

// ---------------- output GEMM: out[4096][1024] = vals(bf16) @ owb^T + o_b  (fp32 out)
__global__ __launch_bounds__(256) void gemm_out_k(
    const u16* __restrict__ A, const u16* __restrict__ Bw,
    const float* __restrict__ bias, float* __restrict__ out) {
  __shared__ u16 As[128][40];
  __shared__ u16 Bs[128][40];
  const int tid = threadIdx.x;
  const int l = tid & 63, w = tid >> 6;
  const int wr = w >> 1, wc = w & 1;
  const int fr = l & 15, kq = (l >> 4) * 8;
  const int bid = blockIdx.x;
  const int tn = (bid % 8) * 128, tm = (bid / 8) * 128;
  const int sr = tid >> 1, sc = (tid & 1) * 16;
  const u16* Ag = A + (size_t)(tm + sr) * 1024 + sc;
  const u16* Bg = Bw + (size_t)(tn + sr) * 1024 + sc;
  f32x4 acc[4][4] = {};
  auto compute = [&]() {
    bf16x8 af[4], bfv[4];
#pragma unroll
    for (int mi = 0; mi < 4; ++mi) af[mi] = *(const bf16x8*)&As[wr * 64 + mi * 16 + fr][kq];
#pragma unroll
    for (int ni = 0; ni < 4; ++ni) bfv[ni] = *(const bf16x8*)&Bs[wc * 64 + ni * 16 + fr][kq];
#pragma unroll
    for (int mi = 0; mi < 4; ++mi)
#pragma unroll
      for (int ni = 0; ni < 4; ++ni)
        acc[mi][ni] = mfma16(af[mi], bfv[ni], acc[mi][ni]);
  };
  bf16x8 aX0, aX1, bX0, bX1, aY0, aY1, bY0, bY1;
  aX0 = *(const bf16x8*)(Ag);     aX1 = *(const bf16x8*)(Ag + 8);
  bX0 = *(const bf16x8*)(Bg);     bX1 = *(const bf16x8*)(Bg + 8);
#pragma unroll 1
  for (int kt = 0; kt < 32; kt += 2) {
    __syncthreads();
    *(bf16x8*)&As[sr][sc] = aX0; *(bf16x8*)&As[sr][sc + 8] = aX1;
    *(bf16x8*)&Bs[sr][sc] = bX0; *(bf16x8*)&Bs[sr][sc + 8] = bX1;
    __syncthreads();
    aY0 = *(const bf16x8*)(Ag + (kt + 1) * 32);
    aY1 = *(const bf16x8*)(Ag + (kt + 1) * 32 + 8);
    bY0 = *(const bf16x8*)(Bg + (kt + 1) * 32);
    bY1 = *(const bf16x8*)(Bg + (kt + 1) * 32 + 8);
    compute();
    __syncthreads();
    *(bf16x8*)&As[sr][sc] = aY0; *(bf16x8*)&As[sr][sc + 8] = aY1;
    *(bf16x8*)&Bs[sr][sc] = bY0; *(bf16x8*)&Bs[sr][sc + 8] = bY1;
    __syncthreads();
    if (kt + 2 < 32) {
      aX0 = *(const bf16x8*)(Ag + (kt + 2) * 32);
      aX1 = *(const bf16x8*)(Ag + (kt + 2) * 32 + 8);
      bX0 = *(const bf16x8*)(Bg + (kt + 2) * 32);
      bX1 = *(const bf16x8*)(Bg + (kt + 2) * 32 + 8);
    }
    compute();
  }
#pragma unroll
  for (int mi = 0; mi < 4; ++mi)
#pragma unroll
    for (int ni = 0; ni < 4; ++ni)
#pragma unroll
      for (int j = 0; j < 4; ++j) {
        int gm = tm + wr * 64 + mi * 16 + (l >> 4) * 4 + j;
        int gn = tn + wc * 64 + ni * 16 + fr;
        out[(size_t)gm * 1024 + gn] = acc[mi][ni][j] + bias[gn];
      }
}

extern "C" void kernel_launch(void* const* d_in, const int* in_sizes, int n_in,
                              void* d_out, int out_size, void* d_ws, size_t ws_size,
                              hipStream_t stream) {
  (void)in_sizes; (void)n_in; (void)out_size; (void)ws_size;
  const float* x    = (const float*)d_in[0];
  const float* qkvw = (const float*)d_in[1];
  const float* qkvb = (const float*)d_in[2];
  const float* ow   = (const float*)d_in[3];
  const float* ob   = (const float*)d_in[4];
  const float* tbl  = (const float*)d_in[5];
  const int*   mask = (const int*)d_in[6];
  float* out = (float*)d_out;
  char* ws = (char*)d_ws;
  u16* tb   = (u16*)(ws);
  u16* tbT  = (u16*)(ws + 20480);
  u16* qb   = (u16*)(ws + 40960);
  u16* kb   = (u16*)(ws + 40960 + 8388608ull);
  u16* vt   = (u16*)(ws + 40960 + 2ull * 8388608ull);
  u16* xbvals = (u16*)(ws + 40960 + 3ull * 8388608ull);   // xb (pre-attn) / vals (post)
  u16* bmq  = (u16*)(ws + 40960 + 4ull * 8388608ull);
  u16* wb   = (u16*)(ws + 40960 + 4ull * 8388608ull + 524288ull);
  u16* owb  = (u16*)(ws + 40960 + 4ull * 8388608ull + 524288ull + 6291456ull);

  prep_table_k<<<dim3(1), dim3(256), 0, stream>>>(tbl, tb, tbT);
  prep_maskq_k<<<dim3(1024), dim3(256), 0, stream>>>(mask, bmq);
  prep_cvt_k<<<dim3(4096), dim3(256), 0, stream>>>(x, qkvw, ow, xbvals, wb, owb);
  gemm_qkv_k<<<dim3(768), dim3(256), 0, stream>>>(xbvals, wb, qkvb, qb, kb, vt);
  attn_k<<<dim3(1024), dim3(256), 0, stream>>>(qb, kb, vt, tb, tbT, bmq, xbvals);
  gemm_out_k<<<dim3(256), dim3(256), 0, stream>>>(xbvals, owb, ob, out);
}